// Round 5
// baseline (76.556 us; speedup 1.0000x reference)
//
#include <hip/hip_runtime.h>
#include <hip/hip_bf16.h>

#define IN_F  8192
#define OUT_F 8192
#define BATCH 16
#define KSPLIT 16
#define KCHUNK (IN_F / KSPLIT)     // 512 k per wave
#define KSTEPS (KCHUNK / 32)       // 16 mfma steps
#define THREADS 256

typedef __attribute__((ext_vector_type(8))) short bf16x8;
typedef __attribute__((ext_vector_type(4))) float f32x4;

// out[b][o] = bias[o]  (re-inits the atomic accumulator every call;
// required every call since the harness does not re-poison between replays)
__global__ __launch_bounds__(256)
void init_out_kernel(const float* __restrict__ bias, float* __restrict__ out)
{
    const int i = blockIdx.x * 256 + threadIdx.x;
    out[i] = bias[i & (OUT_F - 1)];
}

__global__ __launch_bounds__(THREADS, 4)
void gptq_mfma_kernel(const float* __restrict__ x,
                      const int*  __restrict__ qw,
                      const float* __restrict__ scale,
                      float* __restrict__ out)
{
    const int lane = threadIdx.x & 63;
    const int wave = threadIdx.x >> 6;
    const int kidx   = blockIdx.x & (KSPLIT - 1);
    const int rowgrp = blockIdx.x >> 4;
    const int row0 = (rowgrp * 4 + wave) * 16;   // wave's 16 output rows
    const int k0   = kidx * KCHUNK;

    // A-frag: lane holds A[m = lane&15][k = kgrp*8 + j], j=0..7 (m = batch).
    // B-frag: lane holds B[k = kgrp*8 + j][n = lane&15]      (n = out row).
    // Identical per-lane k-addressing for A and B => any internal k
    // permutation cancels in the dot product.
    const int mn   = lane & 15;
    const int kgrp = lane >> 4;

    const float* xsrc = x  + (size_t)mn * IN_F + k0 + kgrp * 8;
    const int*   qsrc = qw + (size_t)(row0 + mn) * IN_F + k0 + kgrp * 8;

    f32x4 acc = {0.f, 0.f, 0.f, 0.f};

    #pragma unroll 4
    for (int s = 0; s < KSTEPS; ++s) {
        const float4 a0 = *reinterpret_cast<const float4*>(xsrc + s * 32);
        const float4 a1 = *reinterpret_cast<const float4*>(xsrc + s * 32 + 4);
        const int4   b0 = *reinterpret_cast<const int4*>(qsrc + s * 32);
        const int4   b1 = *reinterpret_cast<const int4*>(qsrc + s * 32 + 4);

        bf16x8 af, bf;
        af[0] = __bfloat16_as_short(__float2bfloat16(a0.x));
        af[1] = __bfloat16_as_short(__float2bfloat16(a0.y));
        af[2] = __bfloat16_as_short(__float2bfloat16(a0.z));
        af[3] = __bfloat16_as_short(__float2bfloat16(a0.w));
        af[4] = __bfloat16_as_short(__float2bfloat16(a1.x));
        af[5] = __bfloat16_as_short(__float2bfloat16(a1.y));
        af[6] = __bfloat16_as_short(__float2bfloat16(a1.z));
        af[7] = __bfloat16_as_short(__float2bfloat16(a1.w));
        // int4-valued weights (-8..7) are exact in bf16
        bf[0] = __bfloat16_as_short(__float2bfloat16((float)b0.x));
        bf[1] = __bfloat16_as_short(__float2bfloat16((float)b0.y));
        bf[2] = __bfloat16_as_short(__float2bfloat16((float)b0.z));
        bf[3] = __bfloat16_as_short(__float2bfloat16((float)b0.w));
        bf[4] = __bfloat16_as_short(__float2bfloat16((float)b1.x));
        bf[5] = __bfloat16_as_short(__float2bfloat16((float)b1.y));
        bf[6] = __bfloat16_as_short(__float2bfloat16((float)b1.z));
        bf[7] = __bfloat16_as_short(__float2bfloat16((float)b1.w));

        acc = __builtin_amdgcn_mfma_f32_16x16x32_bf16(af, bf, acc, 0, 0, 0);
    }

    // C mapping (m89-verified): col = lane&15 (out row n), row = (lane>>4)*4+v (batch m)
    const float s = scale[0];
    #pragma unroll
    for (int v = 0; v < 4; ++v) {
        const int m = kgrp * 4 + v;
        atomicAdd(out + (size_t)m * OUT_F + row0 + mn, acc[v] * s);
    }
}

extern "C" void kernel_launch(void* const* d_in, const int* in_sizes, int n_in,
                              void* d_out, int out_size, void* d_ws, size_t ws_size,
                              hipStream_t stream) {
    const float* x     = (const float*)d_in[0];
    const int*   qw    = (const int*)d_in[1];
    const float* scale = (const float*)d_in[2];
    const float* bias  = (const float*)d_in[3];
    float*       out   = (float*)d_out;

    init_out_kernel<<<(BATCH * OUT_F) / 256, 256, 0, stream>>>(bias, out);

    // 512 row-waves (8192/16) / 4 waves-per-block = 128 rowgrps x 16 k-splits
    dim3 grid((OUT_F / 16 / 4) * KSPLIT);   // 2048 blocks
    gptq_mfma_kernel<<<grid, THREADS, 0, stream>>>(x, qw, scale, out);
}